// Round 19
// baseline (196.478 us; speedup 1.0000x reference)
//
#include <hip/hip_runtime.h>
#include <math.h>

#define BB 8
#define NN 2048
#define DD 256
#define TT (BB*NN)      // 16384 tokens
#define DP1 257
#define EPSF 1e-6f

typedef _Float16 f16;
typedef __attribute__((ext_vector_type(8))) _Float16 f16x8;
typedef __attribute__((ext_vector_type(4))) float f32x4;

#define BAR() asm volatile("s_barrier" ::: "memory")
#define WAIT_VM(N) asm volatile("s_waitcnt vmcnt(" #N ")" ::: "memory")
#define WAIT_LGKM0() asm volatile("s_waitcnt lgkmcnt(0)" ::: "memory")

__device__ __forceinline__ f32x4 mfma16(f16x8 a, f16x8 b, f32x4 c) {
  return __builtin_amdgcn_mfma_f32_16x16x32_f16(a, b, c, 0, 0, 0);
}
// async global->LDS, 16B/lane; dest = wave-uniform base + lane*16.
__device__ __forceinline__ void gll16(const f16* g, f16* l) {
  __builtin_amdgcn_global_load_lds(
      (const __attribute__((address_space(1))) void*)g,
      (__attribute__((address_space(3))) void*)l, 16, 0, 0);
}

__device__ __forceinline__ float wave_sum(float v) {
#pragma unroll
  for (int m = 1; m < 64; m <<= 1) v += __shfl_xor(v, m);
  return v;
}

// ---------------- K1: one wave per token, shfl-only ----------------
__global__ __launch_bounds__(256) void prep_kernel(
    const float* __restrict__ x, const float* __restrict__ xv,
    float* __restrict__ xtan, f16* __restrict__ xtan_h, f16* __restrict__ vel0_h) {
  const int w = threadIdx.x >> 6, l = threadIdx.x & 63;
  const int tok = blockIdx.x * 4 + w;
  const float* xr = x  + (size_t)tok * DP1;
  const float* vr = xv + (size_t)tok * DP1;
  float x0 = xr[0];
  float sp[4];
  float ss = 0.f;
#pragma unroll
  for (int j = 0; j < 4; j++) { sp[j] = xr[1 + l + 64 * j]; ss = fmaf(sp[j], sp[j], ss); }
  ss = wave_sum(ss);
  float n  = sqrtf(fmaxf(ss, EPSF));
  float dd = acoshf(fmaxf(x0, 1.f + EPSF));
  float scl = dd / n;
  float coef = -vr[0] / (1.f + x0);
  const size_t base = (size_t)tok * DD;
#pragma unroll
  for (int j = 0; j < 4; j++) {
    float xt = scl * sp[j];
    xtan[base + l + 64 * j] = xt;
    xtan_h[base + l + 64 * j] = (f16)xt;
    vel0_h[base + l + 64 * j] = (f16)(vr[1 + l + 64 * j] + coef * sp[j]);
  }
}

// ---------------- weight cast fp32 -> f16, Wh = [Wq;Wk;Wv] ------------------
__global__ __launch_bounds__(256) void wcast_kernel(
    const float* __restrict__ Wq, const float* __restrict__ Wk,
    const float* __restrict__ Wv, f16* __restrict__ Wh) {
  const int m = blockIdx.y;
  const int i = blockIdx.x * 256 + threadIdx.x;
  const float* W = (m == 0) ? Wq : ((m == 1) ? Wk : Wv);
  Wh[(size_t)m * DD * DD + i] = (f16)W[i];
}

// ---------------- merged MFMA GEMM, 128x128 tile, depth-2 prefetch -----------
__global__ __launch_bounds__(256, 2) void gemm_mfma(
    const f16* __restrict__ xtan_h, const f16* __restrict__ vel0_h,
    const f16* __restrict__ Wh,
    f16* __restrict__ qh, f16* __restrict__ kh, f16* __restrict__ vT,
    f16* __restrict__ qvh, f16* __restrict__ kvh,
    const float* __restrict__ bq, const float* __restrict__ bk,
    const float* __restrict__ bv) {
  __shared__ __align__(16) f16 sA[3 * 4096];
  __shared__ __align__(16) f16 sB[3 * 4096];
  const int tid = threadIdx.x;
  const int bm = blockIdx.x * 128;
  const int bn = blockIdx.y * 128;
  const int seg = bn >> 8;                 // 0..4
  const int w = tid >> 6, l = tid & 63;
  const int wr = w >> 1, wc = w & 1;
  f32x4 acc[4][4] = {};
  const f16* Ab = ((seg < 3) ? xtan_h : vel0_h) + (size_t)bm * DD;
  const f16* Bb = Wh + (size_t)((seg < 3) ? bn : (bn - 768)) * DD;

  auto stage = [&](int nx, int buf) {
    const int k0 = nx * 32;
#pragma unroll
    for (int p = 0; p < 2; p++) {
      int u = tid + p * 256;
      int row = u >> 2;
      int q = (u & 3) ^ ((u >> 3) & 3);
      size_t go = (size_t)row * DD + k0 + q * 8;
      size_t lb = (size_t)buf * 4096 + (size_t)(w * 64 + p * 256) * 8;
      gll16(Ab + go, sA + lb);
      gll16(Bb + go, sB + lb);
    }
  };

  stage(0, 0);
  stage(1, 1);
  const int fq = ((l >> 4) ^ ((l >> 1) & 3)) * 8;
  for (int kt = 0; kt < 8; ++kt) {
    if (kt < 6)      { stage(kt + 2, (kt + 2) % 3); WAIT_VM(8); }
    else if (kt == 6){ WAIT_VM(4); }
    else             { WAIT_VM(0); }
    BAR();
    const int co = (kt % 3) * 4096;
    f16x8 af[4], bf[4];
#pragma unroll
    for (int i = 0; i < 4; i++)
      af[i] = *(const f16x8*)(sA + co + (wr * 64 + i * 16 + (l & 15)) * 32 + fq);
#pragma unroll
    for (int j = 0; j < 4; j++)
      bf[j] = *(const f16x8*)(sB + co + (wc * 64 + j * 16 + (l & 15)) * 32 + fq);
    __builtin_amdgcn_s_setprio(1);
#pragma unroll
    for (int i = 0; i < 4; i++)
#pragma unroll
      for (int j = 0; j < 4; j++)
        acc[i][j] = mfma16(af[i], bf[j], acc[i][j]);
    __builtin_amdgcn_s_setprio(0);
    BAR();
  }

  f16* optr = (seg == 0) ? qh : (seg == 1) ? kh : (seg == 2) ? vT : (seg == 3) ? qvh : kvh;
  const float* bias = (seg == 0 || seg == 3) ? bq : (seg == 1 || seg == 4) ? bk : bv;
  const int ot = (seg == 2) ? 1 : 0;
  const int rl = (l >> 4) * 4, cl = l & 15;
#pragma unroll
  for (int i = 0; i < 4; i++) {
#pragma unroll
    for (int j = 0; j < 4; j++) {
      const int col = (bn & 255) + wc * 64 + j * 16 + cl;
      const float bvv = bias[col];
      const int row0 = bm + wr * 64 + i * 16 + rl;
      if (ot == 0) {
#pragma unroll
        for (int r = 0; r < 4; r++)
          optr[(size_t)(row0 + r) * DD + col] = (f16)(acc[i][j][r] + bvv);
      } else {
        __align__(8) f16 tmp[4];
#pragma unroll
        for (int r = 0; r < 4; r++) tmp[r] = (f16)(acc[i][j][r] + bvv);
        f16* dst = optr + ((size_t)((row0 >> 11) * DD + col)) * NN + (row0 & (NN - 1));
        *(uint2*)dst = *(const uint2*)tmp;
      }
    }
  }
}

// ---------------- norms: read-only; scalars only (sinh-scale in logits epi) --
__global__ __launch_bounds__(256) void norms_kernel(
    const f16* __restrict__ qh, const f16* __restrict__ kh,
    const f16* __restrict__ qvh, const f16* __restrict__ kvh,
    float* __restrict__ q0, float* __restrict__ k0v,
    float* __restrict__ q_sq, float* __restrict__ k_sq,
    float* __restrict__ snq, float* __restrict__ snk) {
  const int w = threadIdx.x >> 6, l = threadIdx.x & 63;
  const int tok = blockIdx.x * 4 + w;
  const size_t base = (size_t)tok * DD;
  float sq = 0.f, sk = 0.f, svq = 0.f, svk = 0.f;
#pragma unroll
  for (int j = 0; j < 4; j++) {
    size_t off = base + l + 64 * j;
    float q = (float)qh[off], k = (float)kh[off];
    float qv = (float)qvh[off], kv = (float)kvh[off];
    sq = fmaf(q, q, sq);
    sk = fmaf(k, k, sk);
    svq = fmaf(qv, qv, svq);
    svk = fmaf(kv, kv, svk);
  }
  sq = wave_sum(sq); sk = wave_sum(sk);
  svq = wave_sum(svq); svk = wave_sum(svk);
  if (l == 0) {
    float nq = sqrtf(fmaxf(sq, EPSF));
    float nk = sqrtf(fmaxf(sk, EPSF));
    q0[tok] = coshf(nq);
    k0v[tok] = coshf(nk);
    q_sq[tok] = svq;
    k_sq[tok] = svk;
    snq[tok] = sinhf(nq) / nq;
    snk[tok] = sinhf(nk) / nk;
  }
}

// ---------------- logits: 256-key x 128-query tile, 8 waves, 2 K-sweeps ------
// Wave grid 4(keys) x 2(queries); per-wave frag shape identical to before.
// Staging L=3 gll16/thread/tile; depth-2 counted vmcnt (6/3/0); 2 BAR/phase.
// q/k enter UNSCALED; sinh scale applied in epilogue (inner = snq*snk*accq).
template<int SF>
__global__ __launch_bounds__(512, 2) void logits_mfma(
    const f16* __restrict__ qh, const f16* __restrict__ kh,
    const f16* __restrict__ qvh, const f16* __restrict__ kvh,
    const float* __restrict__ q0a, const float* __restrict__ k0a,
    const float* __restrict__ qsqa, const float* __restrict__ ksqa,
    const float* __restrict__ snqa, const float* __restrict__ snka,
    const float* __restrict__ tau, float* __restrict__ attn,
    f16* __restrict__ slabh, float* __restrict__ psum) {
  __shared__ __align__(16) f16 sA[3 * 8192];   // K-side operand, 256x32
  __shared__ __align__(16) f16 sB[3 * 4096];   // Q-side operand, 128x32
  const int tid = threadIdx.x;
  const int bid = blockIdx.x;
  const int b = bid & 7;
  const int bq = ((bid >> 3) & 15) * 128;   // queries
  const int kti = bid >> 7;                 // key-tile index (0..7)
  const int bk = kti * 256;                 // keys
  const size_t tb = (size_t)b * NN;
  const f16* Q  = qh  + (tb + bq) * DD;
  const f16* Kp = kh  + (tb + bk) * DD;
  const f16* Qv = qvh + (tb + bq) * DD;
  const f16* Kv = kvh + (tb + bk) * DD;
  const int w = tid >> 6, l = tid & 63;
  const int wr = w >> 1, wc = w & 1;        // wr: 0..3 keys, wc: 0..1 queries
  f32x4 accq[4][4] = {}, accv[4][4] = {};
  const int fq = ((l >> 4) ^ ((l >> 1) & 3)) * 8;

  auto stage2 = [&](const f16* Ksrc, const f16* Qsrc, int nx, int buf) {
    const int k0 = nx * 32;
#pragma unroll
    for (int p = 0; p < 2; p++) {           // sA: 256 rows, 2 passes of 512
      int u = tid + p * 512;
      int row = u >> 2;
      int q = (u & 3) ^ ((u >> 3) & 3);
      gll16(Ksrc + (size_t)row * DD + k0 + q * 8,
            sA + (size_t)buf * 8192 + (size_t)(w * 64 + p * 512) * 8);
    }
    {                                        // sB: 128 rows, 1 pass
      int u = tid;
      int row = u >> 2;
      int q = (u & 3) ^ ((u >> 3) & 3);
      gll16(Qsrc + (size_t)row * DD + k0 + q * 8,
            sB + (size_t)buf * 4096 + (size_t)(w * 64) * 8);
    }
  };
  // stage global tile s (0..15) into buf s%3
  auto stageg = [&](int s) {
    if (s < 8) stage2(Kp, Q, s, s % 3);
    else       stage2(Kv, Qv, s - 8, s % 3);
  };

#define LMFMA(ACC, CO)                                                          \
  {                                                                             \
    const int coA = (CO) * 8192, coB = (CO) * 4096;                             \
    f16x8 ak[4], bqf[4];                                                        \
    _Pragma("unroll")                                                           \
    for (int i = 0; i < 4; i++)                                                 \
      ak[i] = *(const f16x8*)(sA + coA + (wr * 64 + i * 16 + (l & 15)) * 32 + fq); \
    _Pragma("unroll")                                                           \
    for (int j = 0; j < 4; j++)                                                 \
      bqf[j] = *(const f16x8*)(sB + coB + (wc * 64 + j * 16 + (l & 15)) * 32 + fq); \
    __builtin_amdgcn_s_setprio(1);                                              \
    _Pragma("unroll")                                                           \
    for (int i = 0; i < 4; i++)                                                 \
      _Pragma("unroll")                                                         \
      for (int j = 0; j < 4; j++)                                               \
        ACC[i][j] = mfma16(ak[i], bqf[j], ACC[i][j]);                           \
    __builtin_amdgcn_s_setprio(0);                                              \
  }

  // prologue: tiles 0,1 in flight (3 loads each)
  stageg(0);
  stageg(1);
  // sweep 1 (tiles 0..7 -> accq); stages tiles 2..9 (8,9 are sweep-2's 0,1)
  for (int g = 0; g < 8; ++g) {
    stageg(g + 2);
    WAIT_VM(6);
    BAR();
    LMFMA(accq, g % 3)
    BAR();
  }
  // sweep 2 (tiles 8..15 -> accv)
  for (int h = 0; h < 8; ++h) {
    if (h < 6)      { stageg(h + 10); WAIT_VM(6); }
    else if (h == 6){ WAIT_VM(3); }
    else            { WAIT_VM(0); }
    BAR();
    LMFMA(accv, (h + 2) % 3)
    BAR();
  }
#undef LMFMA

  const int rl = (l >> 4) * 4, cl = l & 15;
  const float invt = 1.f / fmaxf(tau[0], 1e-3f);
  const float cc = invt * 0.4804530139182014f;   // ln2^2
  float q0r[4], qsr[4], snqr[4];
  float4 k0c[4], ksc[4], snkc[4];
#pragma unroll
  for (int j = 0; j < 4; j++) {
    const int qq = bq + wc * 64 + j * 16 + cl;
    q0r[j] = q0a[tb + qq];
    qsr[j] = qsqa[tb + qq];
    snqr[j] = snqa[tb + qq];
  }
#pragma unroll
  for (int i = 0; i < 4; i++) {
    const int kk = bk + wr * 64 + i * 16 + rl;
    k0c[i] = *(const float4*)(k0a + tb + kk);
    ksc[i] = *(const float4*)(ksqa + tb + kk);
    snkc[i] = *(const float4*)(snka + tb + kk);
  }
  const size_t obase = (size_t)b * NN * NN;
#pragma unroll
  for (int j = 0; j < 4; j++) {
    const int qq = bq + wc * 64 + j * 16 + cl;
    const float q0 = q0r[j], qs = qsr[j], sq = snqr[j];
    float es = 0.f;
#pragma unroll
    for (int i = 0; i < 4; i++) {
      const int kk = bk + wr * 64 + i * 16 + rl;
      const float* k0p = (const float*)&k0c[i];
      const float* ksp = (const float*)&ksc[i];
      const float* skp = (const float*)&snkc[i];
      float4 o;
      float* op = (float*)&o;
      __align__(8) f16 ho[4];
#pragma unroll
      for (int r = 0; r < 4; r++) {
        float sc = sq * skp[r];
        float xv = fmaxf(fmaf(q0, k0p[r], -sc * accq[i][j][r]), 1.f + EPSF);
        float s = sqrtf(fmaf(xv, xv, -1.f));
        float lg = __log2f(xv + s);
        float pen = fmaxf(fmaf(-2.f, accv[i][j][r], qs + ksp[r]), 0.f);
        float lo = fmaf(-cc * lg, lg, -pen);
        float ex = __expf(lo);          // unnormalized exp
        op[r] = ex;
        ho[r] = (f16)ex;
        es += ex;
      }
      if (SF == 1)
        *(uint2*)(slabh + obase + (size_t)qq * NN + kk) = *(const uint2*)ho;
      else
        *(float4*)(attn + obase + (size_t)qq * NN + kk) = o;
    }
    es += __shfl_xor(es, 16);
    es += __shfl_xor(es, 32);
    if ((l >> 4) == 0)
      psum[((size_t)((b * 8 + kti) * 4 + wr)) * NN + qq] = es;
  }
}

// ---------------- fused normalize + PV + exp-map (z) -------------------------
// SF==1: read f16 unnorm-exp from ws slab, write fp32 normalized attn.
// SF==0: read/write fp32 attn in place. V triple-buffered, P two-reg pipeline.
template<int SF>
__global__ __launch_bounds__(256, 2) void pv_fused(
    const float* __restrict__ psum, const f16* __restrict__ vT,
    const f16* __restrict__ slabh, float* __restrict__ attn, float* __restrict__ z) {
  __shared__ __align__(16) f16 sP[2][32 * 32];
  __shared__ __align__(16) f16 sV[3][256 * 32];
  __shared__ float invs_l[32];
  __shared__ float zsum[4][32];
  __shared__ float zsc[32];
  const int tid = threadIdx.x;
  const int bid = blockIdx.x;
  const int b = bid & 7;
  const int row0 = (bid >> 3) * 32;
  const int w = tid >> 6, l = tid & 63;
  float* slab = attn + ((size_t)b * NN + row0) * NN;          // fp32 (write; also read if SF==0)
  const f16* slabr = slabh + ((size_t)b * NN + row0) * NN;    // f16 read if SF==1
  const f16* Vb = vT + (size_t)b * DD * NN;

  if (tid < 32) {
    float s = 0.f;
#pragma unroll 4
    for (int p = 0; p < 32; p++) s += psum[((size_t)b * 32 + p) * NN + row0 + tid];
    invs_l[tid] = 1.f / s;
  }
  __syncthreads();
  const int prow = tid >> 3, pm4 = tid & 7;
  const float myinv = invs_l[prow];
  const int fq = ((l >> 4) ^ ((l >> 1) & 3)) * 8;
  const int spo = prow * 32 + ((pm4 >> 1) ^ ((prow >> 1) & 3)) * 8 + (pm4 & 1) * 4;
  f32x4 acc[2][4] = {};
  float4 pA, pB;

#define STAGEV(nx, vb) do { const int m0_ = (nx) * 32;                          \
    _Pragma("unroll")                                                           \
    for (int p_ = 0; p_ < 4; p_++) {                                            \
      int u_ = tid + p_ * 256;                                                  \
      int d_ = u_ >> 2;                                                         \
      int q_ = (u_ & 3) ^ ((u_ >> 3) & 3);                                      \
      gll16(Vb + (size_t)d_ * NN + m0_ + q_ * 8,                                \
            (f16*)&sV[vb][0] + (size_t)(w * 64 + p_ * 256) * 8);                \
    } } while (0)
#define LOADP(nx, reg) do {                                                     \
    if (SF == 1) {                                                              \
      uint2 rv_ = *(const uint2*)(slabr + (size_t)prow * NN + (nx) * 32 + pm4 * 4); \
      reg.x = __uint_as_float(rv_.x); reg.y = __uint_as_float(rv_.y);           \
    } else {                                                                    \
      reg = *(const float4*)(slab + (size_t)prow * NN + (nx) * 32 + pm4 * 4);   \
    } } while (0)
#define USEP(nx, reg) do {                                                     \
    float e0_, e1_, e2_, e3_;                                                   \
    if (SF == 1) {                                                              \
      uint2 rv_; rv_.x = __float_as_uint(reg.x); rv_.y = __float_as_uint(reg.y);\
      const f16* hp_ = (const f16*)&rv_;                                        \
      e0_ = (float)hp_[0] * myinv; e1_ = (float)hp_[1] * myinv;                 \
      e2_ = (float)hp_[2] * myinv; e3_ = (float)hp_[3] * myinv;                 \
    } else {                                                                    \
      e0_ = reg.x * myinv; e1_ = reg.y * myinv;                                 \
      e2_ = reg.z * myinv; e3_ = reg.w * myinv;                                 \
    }                                                                           \
    float4 ov_ = {e0_, e1_, e2_, e3_};                                          \
    *(float4*)(slab + (size_t)prow * NN + (nx) * 32 + pm4 * 4) = ov_;           \
    __align__(8) f16 tmp_[4] = {(f16)e0_, (f16)e1_, (f16)e2_, (f16)e3_};        \
    *(uint2*)(&sP[(nx) & 1][spo]) = *(const uint2*)tmp_;                        \
  } while (0)
#define COMPUTE(t, vb) do {                                                     \
    f16x8 af_[2], bf_[4];                                                       \
    _Pragma("unroll")                                                           \
    for (int i_ = 0; i_ < 2; i_++)                                              \
      af_[i_] = *(const f16x8*)(&sP[(t) & 1][(i_ * 16 + (l & 15)) * 32 + fq]);  \
    _Pragma("unroll")                                                           \
    for (int j_ = 0; j_ < 4; j_++)                                              \
      bf_[j_] = *(const f16x8*)((const f16*)&sV[vb][0] +                        \
                                (w * 64 + j_ * 16 + (l & 15)) * 32 + fq);       \
    _Pragma("unroll")                                                           \
    for (int i_ = 0; i_ < 2; i_++)                                              \
      _Pragma("unroll")                                                         \
      for (int j_ = 0; j_ < 4; j_++)                                            \
        acc[i_][j_] = mfma16(af_[i_], bf_[j_], acc[i_][j_]);                    \
  } while (0)

  // prologue: tiles 0,1 in flight
  STAGEV(0, 0); LOADP(0, pA);
  STAGEV(1, 1); LOADP(1, pB);
  WAIT_VM(5);          // V0 + P0 done (V1, P1 still in flight)
  USEP(0, pA);
  WAIT_LGKM0();
  BAR();

  int vb0 = 0;         // = t%3 for even t of the pair
  for (int tt = 0; tt < 32; ++tt) {
    {  // t even: NEXT preg = pB, FAR = pA
      const int t = 2 * tt;
      const int vb_t = vb0;
      const int vb_s = (vb0 + 2 > 2) ? vb0 - 1 : vb0 + 2;   // (t+2)%3
      if (t < 62) { STAGEV(t + 2, vb_s); LOADP(t + 2, pA); WAIT_VM(5); }
      else        { WAIT_VM(1); }                            // t==62
      if (t < 63) USEP(t + 1, pB);
      COMPUTE(t, vb_t);
      WAIT_LGKM0();
      BAR();
    }
    {  // t odd: NEXT preg = pA, FAR = pB
      const int t = 2 * tt + 1;
      const int vb_t = (vb0 + 1 > 2) ? vb0 - 2 : vb0 + 1;   // t%3
      const int vb_s = vb0;                                  // (t+2)%3
      if (t < 62)      { STAGEV(t + 2, vb_s); LOADP(t + 2, pB); WAIT_VM(5); }
      else if (t == 62){ WAIT_VM(1); }
      else             { WAIT_VM(0); }                       // t==63
      if (t < 63) USEP(t + 1, pA);
      COMPUTE(t, vb_t);
      WAIT_LGKM0();
      BAR();
    }
    vb0 = (vb0 + 2 > 2) ? vb0 - 1 : vb0 + 2;
  }
#undef STAGEV
#undef LOADP
#undef USEP
#undef COMPUTE

  // z = exp_map0(pad(agg)); acc is already normalized (sP held normalized P).
  const int rl4 = (l >> 4) * 4, cl = l & 15;
  float s2[2][4];
#pragma unroll
  for (int i = 0; i < 2; i++)
#pragma unroll
    for (int r = 0; r < 4; r++) {
      float s = 0.f;
#pragma unroll
      for (int j = 0; j < 4; j++) s = fmaf(acc[i][j][r], acc[i][j][r], s);
#pragma unroll
      for (int m = 1; m < 16; m <<= 1) s += __shfl_xor(s, m);
      s2[i][r] = s;
    }
  if (cl == 0) {
#pragma unroll
    for (int i = 0; i < 2; i++)
#pragma unroll
      for (int r = 0; r < 4; r++)
        zsum[w][i * 16 + rl4 + r] = s2[i][r];
  }
  __syncthreads();
  if (tid < 32) {
    float n2 = zsum[0][tid] + zsum[1][tid] + zsum[2][tid] + zsum[3][tid];
    float nn = sqrtf(fmaxf(n2, EPSF));
    zsc[tid] = sinhf(nn) / nn;
    z[(size_t)(b * NN + row0 + tid) * DP1] = coshf(nn);
  }
  __syncthreads();
#pragma unroll
  for (int i = 0; i < 2; i++)
#pragma unroll
    for (int r = 0; r < 4; r++) {
      const int row = i * 16 + rl4 + r;
      const float sc = zsc[row];
      const size_t zb = (size_t)(b * NN + row0 + row) * DP1 + 1;
#pragma unroll
      for (int j = 0; j < 4; j++)
        z[zb + w * 64 + j * 16 + cl] = acc[i][j][r] * sc;
    }
}

// ---------------- launch -----------------------------------------------------
extern "C" void kernel_launch(void* const* d_in, const int* in_sizes, int n_in,
                              void* d_out, int out_size, void* d_ws, size_t ws_size,
                              hipStream_t stream) {
  const float* x   = (const float*)d_in[0];
  const float* xv  = (const float*)d_in[1];
  const float* Wq  = (const float*)d_in[2];
  const float* bq  = (const float*)d_in[3];
  const float* Wk  = (const float*)d_in[4];
  const float* bk  = (const float*)d_in[5];
  const float* Wv  = (const float*)d_in[6];
  const float* bv  = (const float*)d_in[7];
  const float* tau = (const float*)d_in[8];
  float* out = (float*)d_out;
  char* ws = (char*)d_ws;

  const size_t TD2 = (size_t)TT * DD * 2;   // 8 MB f16 panel

  f16*   qh     = (f16*)(ws);               // GEMM out (unscaled)
  f16*   kh     = (f16*)(ws + TD2);
  f16*   qvh    = (f16*)(ws + 2 * TD2);
  f16*   kvh    = (f16*)(ws + 3 * TD2);
  f16*   vT     = (f16*)(ws + 4 * TD2);
  f16*   xtan_h = (f16*)(ws + 5 * TD2);
  f16*   vel0_h = (f16*)(ws + 6 * TD2);
  f16*   Wh     = (f16*)(ws + 7 * TD2);
  float* psum   = (float*)(ws + 7 * TD2 + 3 * DD * DD * 2);        // [8][32][2048]
  float* q0     = psum + (size_t)BB * 32 * NN;
  float* k0v    = q0 + TT;
  float* q_sq   = q0 + 2 * TT;
  float* k_sq   = q0 + 3 * TT;
  float* snq    = q0 + 4 * TT;
  float* snk    = q0 + 5 * TT;
  // f16 unnorm-exp slab (67 MB) after all fixed allocations
  const size_t fixed_end = 7 * TD2 + 3 * DD * DD * 2 +
                           ((size_t)BB * 32 * NN + 6 * (size_t)TT) * 4;
  f16* slabh = (f16*)(ws + fixed_end);
  const size_t need = fixed_end + (size_t)BB * NN * NN * 2;
  const bool big_ws = (ws_size >= need);

  float* z_out    = out;
  float* attn_out = out + (size_t)TT * DP1;
  float* xtan_out = attn_out + (size_t)BB * NN * NN;

  prep_kernel<<<TT / 4, 256, 0, stream>>>(x, xv, xtan_out, xtan_h, vel0_h);
  wcast_kernel<<<dim3(DD * DD / 256, 3), 256, 0, stream>>>(Wq, Wk, Wv, Wh);

  // merged GEMM: 5 segs = [q_s | k_s | vT | q_vel | k_vel]
  gemm_mfma<<<dim3(TT / 128, 10), 256, 0, stream>>>(
      xtan_h, vel0_h, Wh, qh, kh, vT, qvh, kvh, bq, bk, bv);

  norms_kernel<<<TT / 4, 256, 0, stream>>>(qh, kh, qvh, kvh, q0, k0v, q_sq, k_sq, snq, snk);

  // logits: 256-key x 128-query tiles -> 8 * 16 * 8 = 1024 blocks of 512
  if (big_ws) {
    logits_mfma<1><<<NN / 256 * NN / 128 * BB, 512, 0, stream>>>(
        qh, kh, qvh, kvh, q0, k0v, q_sq, k_sq, snq, snk, tau, attn_out, slabh, psum);
    pv_fused<1><<<NN / 32 * BB, 256, 0, stream>>>(psum, vT, slabh, attn_out, z_out);
  } else {
    logits_mfma<0><<<NN / 256 * NN / 128 * BB, 512, 0, stream>>>(
        qh, kh, qvh, kvh, q0, k0v, q_sq, k_sq, snq, snk, tau, attn_out, slabh, psum);
    pv_fused<0><<<NN / 32 * BB, 256, 0, stream>>>(psum, vT, slabh, attn_out, z_out);
  }
}

// Round 20
// 186.291 us; speedup vs baseline: 1.0547x; 1.0547x over previous
//
#include <hip/hip_runtime.h>
#include <math.h>

#define BB 8
#define NN 2048
#define DD 256
#define TT (BB*NN)      // 16384 tokens
#define DP1 257
#define EPSF 1e-6f

typedef _Float16 f16;
typedef __attribute__((ext_vector_type(8))) _Float16 f16x8;
typedef __attribute__((ext_vector_type(4))) float f32x4;

#define BAR() asm volatile("s_barrier" ::: "memory")
#define WAIT_VM(N) asm volatile("s_waitcnt vmcnt(" #N ")" ::: "memory")
#define WAIT_LGKM0() asm volatile("s_waitcnt lgkmcnt(0)" ::: "memory")

__device__ __forceinline__ f32x4 mfma16(f16x8 a, f16x8 b, f32x4 c) {
  return __builtin_amdgcn_mfma_f32_16x16x32_f16(a, b, c, 0, 0, 0);
}
// async global->LDS, 16B/lane; dest = wave-uniform base + lane*16.
__device__ __forceinline__ void gll16(const f16* g, f16* l) {
  __builtin_amdgcn_global_load_lds(
      (const __attribute__((address_space(1))) void*)g,
      (__attribute__((address_space(3))) void*)l, 16, 0, 0);
}

__device__ __forceinline__ float wave_sum(float v) {
#pragma unroll
  for (int m = 1; m < 64; m <<= 1) v += __shfl_xor(v, m);
  return v;
}

// ---------------- K1: one wave per token, shfl-only ----------------
__global__ __launch_bounds__(256) void prep_kernel(
    const float* __restrict__ x, const float* __restrict__ xv,
    float* __restrict__ xtan, f16* __restrict__ xtan_h, f16* __restrict__ vel0_h) {
  const int w = threadIdx.x >> 6, l = threadIdx.x & 63;
  const int tok = blockIdx.x * 4 + w;
  const float* xr = x  + (size_t)tok * DP1;
  const float* vr = xv + (size_t)tok * DP1;
  float x0 = xr[0];
  float sp[4];
  float ss = 0.f;
#pragma unroll
  for (int j = 0; j < 4; j++) { sp[j] = xr[1 + l + 64 * j]; ss = fmaf(sp[j], sp[j], ss); }
  ss = wave_sum(ss);
  float n  = sqrtf(fmaxf(ss, EPSF));
  float dd = acoshf(fmaxf(x0, 1.f + EPSF));
  float scl = dd / n;
  float coef = -vr[0] / (1.f + x0);
  const size_t base = (size_t)tok * DD;
#pragma unroll
  for (int j = 0; j < 4; j++) {
    float xt = scl * sp[j];
    xtan[base + l + 64 * j] = xt;
    xtan_h[base + l + 64 * j] = (f16)xt;
    vel0_h[base + l + 64 * j] = (f16)(vr[1 + l + 64 * j] + coef * sp[j]);
  }
}

// ---------------- weight cast fp32 -> f16, Wh = [Wq;Wk;Wv] ------------------
__global__ __launch_bounds__(256) void wcast_kernel(
    const float* __restrict__ Wq, const float* __restrict__ Wk,
    const float* __restrict__ Wv, f16* __restrict__ Wh) {
  const int m = blockIdx.y;
  const int i = blockIdx.x * 256 + threadIdx.x;
  const float* W = (m == 0) ? Wq : ((m == 1) ? Wk : Wv);
  Wh[(size_t)m * DD * DD + i] = (f16)W[i];
}

// ---------------- merged MFMA GEMM, 128x128 tile, depth-2 prefetch -----------
__global__ __launch_bounds__(256, 2) void gemm_mfma(
    const f16* __restrict__ xtan_h, const f16* __restrict__ vel0_h,
    const f16* __restrict__ Wh,
    f16* __restrict__ qh, f16* __restrict__ kh, f16* __restrict__ vT,
    f16* __restrict__ qvh, f16* __restrict__ kvh,
    const float* __restrict__ bq, const float* __restrict__ bk,
    const float* __restrict__ bv) {
  __shared__ __align__(16) f16 sA[3 * 4096];
  __shared__ __align__(16) f16 sB[3 * 4096];
  const int tid = threadIdx.x;
  const int bm = blockIdx.x * 128;
  const int bn = blockIdx.y * 128;
  const int seg = bn >> 8;                 // 0..4
  const int w = tid >> 6, l = tid & 63;
  const int wr = w >> 1, wc = w & 1;
  f32x4 acc[4][4] = {};
  const f16* Ab = ((seg < 3) ? xtan_h : vel0_h) + (size_t)bm * DD;
  const f16* Bb = Wh + (size_t)((seg < 3) ? bn : (bn - 768)) * DD;

  auto stage = [&](int nx, int buf) {
    const int k0 = nx * 32;
#pragma unroll
    for (int p = 0; p < 2; p++) {
      int u = tid + p * 256;
      int row = u >> 2;
      int q = (u & 3) ^ ((u >> 3) & 3);
      size_t go = (size_t)row * DD + k0 + q * 8;
      size_t lb = (size_t)buf * 4096 + (size_t)(w * 64 + p * 256) * 8;
      gll16(Ab + go, sA + lb);
      gll16(Bb + go, sB + lb);
    }
  };

  stage(0, 0);
  stage(1, 1);
  const int fq = ((l >> 4) ^ ((l >> 1) & 3)) * 8;
  for (int kt = 0; kt < 8; ++kt) {
    if (kt < 6)      { stage(kt + 2, (kt + 2) % 3); WAIT_VM(8); }
    else if (kt == 6){ WAIT_VM(4); }
    else             { WAIT_VM(0); }
    BAR();
    const int co = (kt % 3) * 4096;
    f16x8 af[4], bf[4];
#pragma unroll
    for (int i = 0; i < 4; i++)
      af[i] = *(const f16x8*)(sA + co + (wr * 64 + i * 16 + (l & 15)) * 32 + fq);
#pragma unroll
    for (int j = 0; j < 4; j++)
      bf[j] = *(const f16x8*)(sB + co + (wc * 64 + j * 16 + (l & 15)) * 32 + fq);
    __builtin_amdgcn_s_setprio(1);
#pragma unroll
    for (int i = 0; i < 4; i++)
#pragma unroll
      for (int j = 0; j < 4; j++)
        acc[i][j] = mfma16(af[i], bf[j], acc[i][j]);
    __builtin_amdgcn_s_setprio(0);
    BAR();
  }

  f16* optr = (seg == 0) ? qh : (seg == 1) ? kh : (seg == 2) ? vT : (seg == 3) ? qvh : kvh;
  const float* bias = (seg == 0 || seg == 3) ? bq : (seg == 1 || seg == 4) ? bk : bv;
  const int ot = (seg == 2) ? 1 : 0;
  const int rl = (l >> 4) * 4, cl = l & 15;
#pragma unroll
  for (int i = 0; i < 4; i++) {
#pragma unroll
    for (int j = 0; j < 4; j++) {
      const int col = (bn & 255) + wc * 64 + j * 16 + cl;
      const float bvv = bias[col];
      const int row0 = bm + wr * 64 + i * 16 + rl;
      if (ot == 0) {
#pragma unroll
        for (int r = 0; r < 4; r++)
          optr[(size_t)(row0 + r) * DD + col] = (f16)(acc[i][j][r] + bvv);
      } else {
        __align__(8) f16 tmp[4];
#pragma unroll
        for (int r = 0; r < 4; r++) tmp[r] = (f16)(acc[i][j][r] + bvv);
        f16* dst = optr + ((size_t)((row0 >> 11) * DD + col)) * NN + (row0 & (NN - 1));
        *(uint2*)dst = *(const uint2*)tmp;
      }
    }
  }
}

// ---------------- norms: read-only; scalars only (sinh-scale in logits epi) --
__global__ __launch_bounds__(256) void norms_kernel(
    const f16* __restrict__ qh, const f16* __restrict__ kh,
    const f16* __restrict__ qvh, const f16* __restrict__ kvh,
    float* __restrict__ q0, float* __restrict__ k0v,
    float* __restrict__ q_sq, float* __restrict__ k_sq,
    float* __restrict__ snq, float* __restrict__ snk) {
  const int w = threadIdx.x >> 6, l = threadIdx.x & 63;
  const int tok = blockIdx.x * 4 + w;
  const size_t base = (size_t)tok * DD;
  float sq = 0.f, sk = 0.f, svq = 0.f, svk = 0.f;
#pragma unroll
  for (int j = 0; j < 4; j++) {
    size_t off = base + l + 64 * j;
    float q = (float)qh[off], k = (float)kh[off];
    float qv = (float)qvh[off], kv = (float)kvh[off];
    sq = fmaf(q, q, sq);
    sk = fmaf(k, k, sk);
    svq = fmaf(qv, qv, svq);
    svk = fmaf(kv, kv, svk);
  }
  sq = wave_sum(sq); sk = wave_sum(sk);
  svq = wave_sum(svq); svk = wave_sum(svk);
  if (l == 0) {
    float nq = sqrtf(fmaxf(sq, EPSF));
    float nk = sqrtf(fmaxf(sk, EPSF));
    q0[tok] = coshf(nq);
    k0v[tok] = coshf(nk);
    q_sq[tok] = svq;
    k_sq[tok] = svk;
    snq[tok] = sinhf(nq) / nq;
    snk[tok] = sinhf(nk) / nk;
  }
}

// ---------------- logits: dual MFMA, TWO K-sweeps, depth-2 prefetch ----------
// 128x128 tile, 4 waves. Triple-buffered 48KB LDS; sweep-1's last two stages
// prefetch sweep-2's tiles 0,1 (vmcnt never drains mid-kernel).
// q/k enter UNSCALED; sinh scale applied in epilogue (inner = snq*snk*accq).
// SF==1: write f16 unnorm-exp to ws slab; SF==0: fp32 to attn.
template<int SF>
__global__ __launch_bounds__(256, 2) void logits_mfma(
    const f16* __restrict__ qh, const f16* __restrict__ kh,
    const f16* __restrict__ qvh, const f16* __restrict__ kvh,
    const float* __restrict__ q0a, const float* __restrict__ k0a,
    const float* __restrict__ qsqa, const float* __restrict__ ksqa,
    const float* __restrict__ snqa, const float* __restrict__ snka,
    const float* __restrict__ tau, float* __restrict__ attn,
    f16* __restrict__ slabh, float* __restrict__ psum) {
  __shared__ __align__(16) f16 sA[3 * 4096];   // K-side operand
  __shared__ __align__(16) f16 sB[3 * 4096];   // Q-side operand
  const int tid = threadIdx.x;
  const int bid = blockIdx.x;
  const int b = bid & 7;
  const int bq = ((bid >> 3) & 15) * 128;   // queries
  const int kti = bid >> 7;                 // key-tile index
  const int bk = kti * 128;                 // keys
  const size_t tb = (size_t)b * NN;
  const f16* Q  = qh  + (tb + bq) * DD;
  const f16* Kp = kh  + (tb + bk) * DD;
  const f16* Qv = qvh + (tb + bq) * DD;
  const f16* Kv = kvh + (tb + bk) * DD;
  const int w = tid >> 6, l = tid & 63;
  const int wr = w >> 1, wc = w & 1;
  f32x4 accq[4][4] = {}, accv[4][4] = {};
  const int fq = ((l >> 4) ^ ((l >> 1) & 3)) * 8;

  auto stage2 = [&](const f16* Ksrc, const f16* Qsrc, int nx, int buf) {
    const int k0 = nx * 32;
#pragma unroll
    for (int p = 0; p < 2; p++) {
      int u = tid + p * 256;
      int row = u >> 2;
      int q = (u & 3) ^ ((u >> 3) & 3);
      size_t go = (size_t)row * DD + k0 + q * 8;
      size_t lb = (size_t)buf * 4096 + (size_t)(w * 64 + p * 256) * 8;
      gll16(Ksrc + go, sA + lb);
      gll16(Qsrc + go, sB + lb);
    }
  };

#define LMFMA(ACC, CO)                                                          \
  {                                                                             \
    const int co = (CO) * 4096;                                                 \
    f16x8 ak[4], bqf[4];                                                        \
    _Pragma("unroll")                                                           \
    for (int i = 0; i < 4; i++)                                                 \
      ak[i] = *(const f16x8*)(sA + co + (wr * 64 + i * 16 + (l & 15)) * 32 + fq); \
    _Pragma("unroll")                                                           \
    for (int j = 0; j < 4; j++)                                                 \
      bqf[j] = *(const f16x8*)(sB + co + (wc * 64 + j * 16 + (l & 15)) * 32 + fq); \
    __builtin_amdgcn_s_setprio(1);                                              \
    _Pragma("unroll")                                                           \
    for (int i = 0; i < 4; i++)                                                 \
      _Pragma("unroll")                                                         \
      for (int j = 0; j < 4; j++)                                               \
        ACC[i][j] = mfma16(ak[i], bqf[j], ACC[i][j]);                           \
    __builtin_amdgcn_s_setprio(0);                                              \
  }

  // prologue: global tiles 0,1 (sweep-1 tiles 0,1)
  stage2(Kp, Q, 0, 0);
  stage2(Kp, Q, 1, 1);
  // sweep 1: global tile g = kt, buf = g%3; stage global g+2
  for (int kt = 0; kt < 8; ++kt) {
    const int s = kt + 2;
    if (s < 8) stage2(Kp, Q, s, s % 3);
    else       stage2(Kv, Qv, s - 8, s % 3);   // s=8,9 -> sweep-2 tiles 0,1
    WAIT_VM(8);
    BAR();
    LMFMA(accq, kt % 3)
    BAR();
  }
  // sweep 2: global tile g = 8+kt, buf = (kt+2)%3; stage global g+2 = tile kt+2
  for (int kt = 0; kt < 8; ++kt) {
    if (kt < 6)      { stage2(Kv, Qv, kt + 2, (kt + 1) % 3); WAIT_VM(8); }
    else if (kt == 6){ WAIT_VM(4); }
    else             { WAIT_VM(0); }
    BAR();
    LMFMA(accv, (kt + 2) % 3)
    BAR();
  }
#undef LMFMA

  const int rl = (l >> 4) * 4, cl = l & 15;
  const float invt = 1.f / fmaxf(tau[0], 1e-3f);
  const float cc = invt * 0.4804530139182014f;   // ln2^2
  float q0r[4], qsr[4], snqr[4];
  float4 k0c[4], ksc[4], snkc[4];
#pragma unroll
  for (int j = 0; j < 4; j++) {
    const int qq = bq + wc * 64 + j * 16 + cl;
    q0r[j] = q0a[tb + qq];
    qsr[j] = qsqa[tb + qq];
    snqr[j] = snqa[tb + qq];
  }
#pragma unroll
  for (int i = 0; i < 4; i++) {
    const int kk = bk + wr * 64 + i * 16 + rl;
    k0c[i] = *(const float4*)(k0a + tb + kk);
    ksc[i] = *(const float4*)(ksqa + tb + kk);
    snkc[i] = *(const float4*)(snka + tb + kk);
  }
  const size_t obase = (size_t)b * NN * NN;
#pragma unroll
  for (int j = 0; j < 4; j++) {
    const int qq = bq + wc * 64 + j * 16 + cl;
    const float q0 = q0r[j], qs = qsr[j], sq = snqr[j];
    float es = 0.f;
#pragma unroll
    for (int i = 0; i < 4; i++) {
      const int kk = bk + wr * 64 + i * 16 + rl;
      const float* k0p = (const float*)&k0c[i];
      const float* ksp = (const float*)&ksc[i];
      const float* skp = (const float*)&snkc[i];
      float4 o;
      float* op = (float*)&o;
      __align__(8) f16 ho[4];
#pragma unroll
      for (int r = 0; r < 4; r++) {
        float sc = sq * skp[r];
        float xv = fmaxf(fmaf(q0, k0p[r], -sc * accq[i][j][r]), 1.f + EPSF);
        float s = sqrtf(fmaf(xv, xv, -1.f));
        float lg = __log2f(xv + s);
        float pen = fmaxf(fmaf(-2.f, accv[i][j][r], qs + ksp[r]), 0.f);
        float lo = fmaf(-cc * lg, lg, -pen);
        float ex = __expf(lo);          // unnormalized exp
        op[r] = ex;
        ho[r] = (f16)ex;
        es += ex;
      }
      if (SF == 1)
        *(uint2*)(slabh + obase + (size_t)qq * NN + kk) = *(const uint2*)ho;
      else
        *(float4*)(attn + obase + (size_t)qq * NN + kk) = o;
    }
    es += __shfl_xor(es, 16);
    es += __shfl_xor(es, 32);
    if ((l >> 4) == 0)
      psum[((size_t)(b * 16 + kti) * 2 + wr) * NN + qq] = es;
  }
}

// ---------------- fused normalize + PV + exp-map (z) -------------------------
// SF==1: read f16 unnorm-exp from ws slab, write fp32 normalized attn.
// SF==0: read/write fp32 attn in place. V triple-buffered, P two-reg pipeline.
template<int SF>
__global__ __launch_bounds__(256, 2) void pv_fused(
    const float* __restrict__ psum, const f16* __restrict__ vT,
    const f16* __restrict__ slabh, float* __restrict__ attn, float* __restrict__ z) {
  __shared__ __align__(16) f16 sP[2][32 * 32];
  __shared__ __align__(16) f16 sV[3][256 * 32];
  __shared__ float invs_l[32];
  __shared__ float zsum[4][32];
  __shared__ float zsc[32];
  const int tid = threadIdx.x;
  const int bid = blockIdx.x;
  const int b = bid & 7;
  const int row0 = (bid >> 3) * 32;
  const int w = tid >> 6, l = tid & 63;
  float* slab = attn + ((size_t)b * NN + row0) * NN;          // fp32 (write; also read if SF==0)
  const f16* slabr = slabh + ((size_t)b * NN + row0) * NN;    // f16 read if SF==1
  const f16* Vb = vT + (size_t)b * DD * NN;

  if (tid < 32) {
    float s = 0.f;
#pragma unroll 4
    for (int p = 0; p < 32; p++) s += psum[((size_t)b * 32 + p) * NN + row0 + tid];
    invs_l[tid] = 1.f / s;
  }
  __syncthreads();
  const int prow = tid >> 3, pm4 = tid & 7;
  const float myinv = invs_l[prow];
  const int fq = ((l >> 4) ^ ((l >> 1) & 3)) * 8;
  const int spo = prow * 32 + ((pm4 >> 1) ^ ((prow >> 1) & 3)) * 8 + (pm4 & 1) * 4;
  f32x4 acc[2][4] = {};
  float4 pA, pB;

#define STAGEV(nx, vb) do { const int m0_ = (nx) * 32;                          \
    _Pragma("unroll")                                                           \
    for (int p_ = 0; p_ < 4; p_++) {                                            \
      int u_ = tid + p_ * 256;                                                  \
      int d_ = u_ >> 2;                                                         \
      int q_ = (u_ & 3) ^ ((u_ >> 3) & 3);                                      \
      gll16(Vb + (size_t)d_ * NN + m0_ + q_ * 8,                                \
            (f16*)&sV[vb][0] + (size_t)(w * 64 + p_ * 256) * 8);                \
    } } while (0)
#define LOADP(nx, reg) do {                                                     \
    if (SF == 1) {                                                              \
      uint2 rv_ = *(const uint2*)(slabr + (size_t)prow * NN + (nx) * 32 + pm4 * 4); \
      reg.x = __uint_as_float(rv_.x); reg.y = __uint_as_float(rv_.y);           \
    } else {                                                                    \
      reg = *(const float4*)(slab + (size_t)prow * NN + (nx) * 32 + pm4 * 4);   \
    } } while (0)
#define USEP(nx, reg) do {                                                      \
    float e0_, e1_, e2_, e3_;                                                   \
    if (SF == 1) {                                                              \
      uint2 rv_; rv_.x = __float_as_uint(reg.x); rv_.y = __float_as_uint(reg.y);\
      const f16* hp_ = (const f16*)&rv_;                                        \
      e0_ = (float)hp_[0] * myinv; e1_ = (float)hp_[1] * myinv;                 \
      e2_ = (float)hp_[2] * myinv; e3_ = (float)hp_[3] * myinv;                 \
    } else {                                                                    \
      e0_ = reg.x * myinv; e1_ = reg.y * myinv;                                 \
      e2_ = reg.z * myinv; e3_ = reg.w * myinv;                                 \
    }                                                                           \
    float4 ov_ = {e0_, e1_, e2_, e3_};                                          \
    *(float4*)(slab + (size_t)prow * NN + (nx) * 32 + pm4 * 4) = ov_;           \
    __align__(8) f16 tmp_[4] = {(f16)e0_, (f16)e1_, (f16)e2_, (f16)e3_};        \
    *(uint2*)(&sP[(nx) & 1][spo]) = *(const uint2*)tmp_;                        \
  } while (0)
#define COMPUTE(t, vb) do {                                                     \
    f16x8 af_[2], bf_[4];                                                       \
    _Pragma("unroll")                                                           \
    for (int i_ = 0; i_ < 2; i_++)                                              \
      af_[i_] = *(const f16x8*)(&sP[(t) & 1][(i_ * 16 + (l & 15)) * 32 + fq]);  \
    _Pragma("unroll")                                                           \
    for (int j_ = 0; j_ < 4; j_++)                                              \
      bf_[j_] = *(const f16x8*)((const f16*)&sV[vb][0] +                        \
                                (w * 64 + j_ * 16 + (l & 15)) * 32 + fq);       \
    _Pragma("unroll")                                                           \
    for (int i_ = 0; i_ < 2; i_++)                                              \
      _Pragma("unroll")                                                         \
      for (int j_ = 0; j_ < 4; j_++)                                            \
        acc[i_][j_] = mfma16(af_[i_], bf_[j_], acc[i_][j_]);                    \
  } while (0)

  // prologue: tiles 0,1 in flight
  STAGEV(0, 0); LOADP(0, pA);
  STAGEV(1, 1); LOADP(1, pB);
  WAIT_VM(5);          // V0 + P0 done (V1, P1 still in flight)
  USEP(0, pA);
  WAIT_LGKM0();
  BAR();

  int vb0 = 0;         // = t%3 for even t of the pair
  for (int tt = 0; tt < 32; ++tt) {
    {  // t even: NEXT preg = pB, FAR = pA
      const int t = 2 * tt;
      const int vb_t = vb0;
      const int vb_s = (vb0 + 2 > 2) ? vb0 - 1 : vb0 + 2;   // (t+2)%3
      if (t < 62) { STAGEV(t + 2, vb_s); LOADP(t + 2, pA); WAIT_VM(5); }
      else        { WAIT_VM(1); }                            // t==62
      if (t < 63) USEP(t + 1, pB);
      COMPUTE(t, vb_t);
      WAIT_LGKM0();
      BAR();
    }
    {  // t odd: NEXT preg = pA, FAR = pB
      const int t = 2 * tt + 1;
      const int vb_t = (vb0 + 1 > 2) ? vb0 - 2 : vb0 + 1;   // t%3
      const int vb_s = vb0;                                  // (t+2)%3
      if (t < 62)      { STAGEV(t + 2, vb_s); LOADP(t + 2, pB); WAIT_VM(5); }
      else if (t == 62){ WAIT_VM(1); }
      else             { WAIT_VM(0); }                       // t==63
      if (t < 63) USEP(t + 1, pA);
      COMPUTE(t, vb_t);
      WAIT_LGKM0();
      BAR();
    }
    vb0 = (vb0 + 2 > 2) ? vb0 - 1 : vb0 + 2;
  }
#undef STAGEV
#undef LOADP
#undef USEP
#undef COMPUTE

  // z = exp_map0(pad(agg)); acc is already normalized (sP held normalized P).
  const int rl4 = (l >> 4) * 4, cl = l & 15;
  float s2[2][4];
#pragma unroll
  for (int i = 0; i < 2; i++)
#pragma unroll
    for (int r = 0; r < 4; r++) {
      float s = 0.f;
#pragma unroll
      for (int j = 0; j < 4; j++) s = fmaf(acc[i][j][r], acc[i][j][r], s);
#pragma unroll
      for (int m = 1; m < 16; m <<= 1) s += __shfl_xor(s, m);
      s2[i][r] = s;
    }
  if (cl == 0) {
#pragma unroll
    for (int i = 0; i < 2; i++)
#pragma unroll
      for (int r = 0; r < 4; r++)
        zsum[w][i * 16 + rl4 + r] = s2[i][r];
  }
  __syncthreads();
  if (tid < 32) {
    float n2 = zsum[0][tid] + zsum[1][tid] + zsum[2][tid] + zsum[3][tid];
    float nn = sqrtf(fmaxf(n2, EPSF));
    zsc[tid] = sinhf(nn) / nn;
    z[(size_t)(b * NN + row0 + tid) * DP1] = coshf(nn);
  }
  __syncthreads();
#pragma unroll
  for (int i = 0; i < 2; i++)
#pragma unroll
    for (int r = 0; r < 4; r++) {
      const int row = i * 16 + rl4 + r;
      const float sc = zsc[row];
      const size_t zb = (size_t)(b * NN + row0 + row) * DP1 + 1;
#pragma unroll
      for (int j = 0; j < 4; j++)
        z[zb + w * 64 + j * 16 + cl] = acc[i][j][r] * sc;
    }
}

// ---------------- launch -----------------------------------------------------
extern "C" void kernel_launch(void* const* d_in, const int* in_sizes, int n_in,
                              void* d_out, int out_size, void* d_ws, size_t ws_size,
                              hipStream_t stream) {
  const float* x   = (const float*)d_in[0];
  const float* xv  = (const float*)d_in[1];
  const float* Wq  = (const float*)d_in[2];
  const float* bq  = (const float*)d_in[3];
  const float* Wk  = (const float*)d_in[4];
  const float* bk  = (const float*)d_in[5];
  const float* Wv  = (const float*)d_in[6];
  const float* bv  = (const float*)d_in[7];
  const float* tau = (const float*)d_in[8];
  float* out = (float*)d_out;
  char* ws = (char*)d_ws;

  const size_t TD2 = (size_t)TT * DD * 2;   // 8 MB f16 panel

  f16*   qh     = (f16*)(ws);               // GEMM out (unscaled)
  f16*   kh     = (f16*)(ws + TD2);
  f16*   qvh    = (f16*)(ws + 2 * TD2);
  f16*   kvh    = (f16*)(ws + 3 * TD2);
  f16*   vT     = (f16*)(ws + 4 * TD2);
  f16*   xtan_h = (f16*)(ws + 5 * TD2);
  f16*   vel0_h = (f16*)(ws + 6 * TD2);
  f16*   Wh     = (f16*)(ws + 7 * TD2);
  float* psum   = (float*)(ws + 7 * TD2 + 3 * DD * DD * 2);        // [8][32][2048]
  float* q0     = psum + (size_t)BB * 32 * NN;
  float* k0v    = q0 + TT;
  float* q_sq   = q0 + 2 * TT;
  float* k_sq   = q0 + 3 * TT;
  float* snq    = q0 + 4 * TT;
  float* snk    = q0 + 5 * TT;
  // f16 unnorm-exp slab (67 MB) after all fixed allocations
  const size_t fixed_end = 7 * TD2 + 3 * DD * DD * 2 +
                           ((size_t)BB * 32 * NN + 6 * (size_t)TT) * 4;
  f16* slabh = (f16*)(ws + fixed_end);
  const size_t need = fixed_end + (size_t)BB * NN * NN * 2;
  const bool big_ws = (ws_size >= need);

  float* z_out    = out;
  float* attn_out = out + (size_t)TT * DP1;
  float* xtan_out = attn_out + (size_t)BB * NN * NN;

  prep_kernel<<<TT / 4, 256, 0, stream>>>(x, xv, xtan_out, xtan_h, vel0_h);
  wcast_kernel<<<dim3(DD * DD / 256, 3), 256, 0, stream>>>(Wq, Wk, Wv, Wh);

  // merged GEMM: 5 segs = [q_s | k_s | vT | q_vel | k_vel]
  gemm_mfma<<<dim3(TT / 128, 10), 256, 0, stream>>>(
      xtan_h, vel0_h, Wh, qh, kh, vT, qvh, kvh, bq, bk, bv);

  norms_kernel<<<TT / 4, 256, 0, stream>>>(qh, kh, qvh, kvh, q0, k0v, q_sq, k_sq, snq, snk);

  if (big_ws) {
    logits_mfma<1><<<NN / 128 * NN / 128 * BB, 256, 0, stream>>>(
        qh, kh, qvh, kvh, q0, k0v, q_sq, k_sq, snq, snk, tau, attn_out, slabh, psum);
    pv_fused<1><<<NN / 32 * BB, 256, 0, stream>>>(psum, vT, slabh, attn_out, z_out);
  } else {
    logits_mfma<0><<<NN / 128 * NN / 128 * BB, 256, 0, stream>>>(
        qh, kh, qvh, kvh, q0, k0v, q_sq, k_sq, snq, snk, tau, attn_out, slabh, psum);
    pv_fused<0><<<NN / 32 * BB, 256, 0, stream>>>(psum, vT, slabh, attn_out, z_out);
  }
}